// Round 14
// baseline (149.609 us; speedup 1.0000x reference)
//
#include <hip/hip_runtime.h>

#define V_N 50000
#define C_N 125000
#define L_N 500000
#define NCH2 31250  // C_N/4 sub-chains of 4 clauses
// D = 128

typedef __attribute__((ext_vector_type(8))) short short8;
typedef __attribute__((ext_vector_type(4))) float f32x4;

__device__ inline unsigned short f2bf(float f) {
  union { float f; unsigned u; } v; v.f = f;
  unsigned r = v.u + 0x7FFFu + ((v.u >> 16) & 1u);
  return (unsigned short)(r >> 16);
}
__device__ inline float bf2f(unsigned short h) {
  union { unsigned u; float f; } v; v.u = ((unsigned)h) << 16;
  return v.f;
}
__device__ inline float sigm(float x) { return 1.f / (1.f + __expf(-x)); }

// f32 -> OCP fp8 e4m3fn (RNE on mantissa, saturate to 448, denormals ok)
__device__ inline unsigned char f2e4m3(float f) {
  union { float f; unsigned u; } v; v.f = f;
  unsigned s = (v.u >> 24) & 0x80u;
  v.u &= 0x7FFFFFFFu;  // abs
  if (!(v.f == v.f)) return (unsigned char)(s | 0x7E);  // NaN -> max (won't occur)
  if (v.f < 0.015625f) {  // below min normal 2^-6: denormal, step 2^-9
    int m = (int)(v.f * 512.f + 0.5f);
    return (unsigned char)(s | m);  // m<=8; m==8 encodes 2^-6 exactly
  }
  unsigned add = 0x7FFFFu + ((v.u >> 20) & 1u);
  unsigned u2 = v.u + add;
  int ef = (int)((u2 >> 23) & 0xFF) - 127 + 7;
  unsigned mant = (u2 >> 20) & 7u;
  if (ef > 15 || (ef == 15 && mant == 7)) { ef = 15; mant = 6; }  // sat 448
  return (unsigned char)(s | ((unsigned)ef << 3) | mant);
}

struct WPtrs { const float* w[11]; };

// Fused front kernel: block-range dispatch of
//   [0,704)            k_prep: 11 weights -> fragment-ordered bf16 layout
//   [704,2658)         k_meta: pmeta[i] = var | sign<<16 | (clause&63)<<17
//   [2658,2781)        k_bnd:  bnd[i] = lower_bound(lit_clause, i*4)
//   [2781,3270)        k_hist: dst[i] = atomicAdd(&cnt[clause_var[i]],1)
__global__ __launch_bounds__(256) void k_front(
    WPtrs p, unsigned short* __restrict__ wt,
    const int* __restrict__ lit_var, const int* __restrict__ lit_sign,
    const int* __restrict__ lit_clause, int* __restrict__ pmeta,
    int* __restrict__ bnd, const int* __restrict__ clause_var,
    int* __restrict__ cnt, int* __restrict__ dst) {
  int b = blockIdx.x;
  if (b < 704) {
    int idx = b * 256 + threadIdx.x;  // 11*16384 total, exact
    int m = idx >> 14;
    int j = idx & 16383;          // input-linear: j = k*128 + col
    int k = j >> 7, col = j & 127;
    float val = p.w[m][j];        // coalesced read
    int chunk = ((col >> 5) << 3) + (((col >> 4) & 1) << 2) + (k >> 5);
    int off = (((k >> 3) & 3) << 7) + ((col & 15) << 3) + (k & 7);
    wt[m * 16384 + chunk * 512 + off] = f2bf(val);
  } else if (b < 2658) {
    int i = (b - 704) * 256 + threadIdx.x;
    if (i < L_N)
      pmeta[i] = lit_var[i] | (lit_sign[i] << 16) | ((lit_clause[i] & 63) << 17);
  } else if (b < 2781) {
    int i = (b - 2658) * 256 + threadIdx.x;
    if (i <= NCH2) {
      int key = i * 4;
      int lo = 0, hi = L_N;
      while (lo < hi) {
        int mid = (lo + hi) >> 1;
        if (lit_clause[mid] < key) lo = mid + 1; else hi = mid;
      }
      bnd[i] = lo;
    }
  } else {
    int i = (b - 2781) * 256 + threadIdx.x;
    if (i < C_N) {
      int v = clause_var[i];
      dst[i] = atomicAdd(&cnt[v], 1);
    }
  }
}

// ---- register-resident B fragments: wave tile = N rows x 32 cols ----
__device__ inline void load_bfrags(const unsigned short* __restrict__ Wt,
                                   short8 B[2][4], int wave, int lane) {
#pragma unroll
  for (int ct = 0; ct < 2; ++ct)
#pragma unroll
    for (int ks = 0; ks < 4; ++ks)
      B[ct][ks] = *(const short8*)(Wt + (((wave << 3) + (ct << 2) + ks) << 9) +
                                   (lane << 3));
}

// 32-row tile GEMM (k_tables / k_gru / k_sc_clause epilogue)
__device__ inline void gemm_reg32(const unsigned short (*__restrict__ xs)[136],
                                  const short8 B[2][4], f32x4 acc[2][2], int lane) {
  const int lan15 = lane & 15, kq = lane >> 4;
#pragma unroll
  for (int ks = 0; ks < 4; ++ks) {
#pragma unroll
    for (int rt = 0; rt < 2; ++rt) {
      short8 a = *(const short8*)(&xs[rt * 16 + lan15][ks * 32 + kq * 8]);
#pragma unroll
      for (int ct = 0; ct < 2; ++ct)
        acc[rt][ct] = __builtin_amdgcn_mfma_f32_16x16x32_bf16(a, B[ct][ks], acc[rt][ct], 0, 0, 0);
    }
  }
}

__device__ inline void zero_acc2(f32x4 acc[2][2]) {
#pragma unroll
  for (int rt = 0; rt < 2; ++rt)
#pragma unroll
    for (int ct = 0; ct < 2; ++ct) acc[rt][ct] = (f32x4)(0.f);
}

// stage 32 f32 rows -> bf16 LDS tile (zero-pad past nrows); 16 cols/thread
__device__ inline void stage_f32_32(const float* __restrict__ base, long vb, int nrows,
                                    unsigned short (*__restrict__ dst)[136], int tid) {
  int r = tid >> 3, cq = (tid & 7) * 16;
  long v = vb + r;
  bool valid = v < nrows;
  const float* src = valid ? base + v * 128 : base;
#pragma unroll
  for (int j = 0; j < 16; j += 4) {
    float4 x4 = *(const float4*)(src + cq + j);
    if (!valid) { x4.x = 0.f; x4.y = 0.f; x4.z = 0.f; x4.w = 0.f; }
    dst[r][cq + j + 0] = f2bf(x4.x);
    dst[r][cq + j + 1] = f2bf(x4.y);
    dst[r][cq + j + 2] = f2bf(x4.z);
    dst[r][cq + j + 3] = f2bf(x4.w);
  }
}

// Phase 1a: t_pos8[v] = fp8(combine(vars[v]));
//           t_neg8[v] = fp8(combine(vars[v]@negW+negb))
__global__ __launch_bounds__(256, 2) void k_tables(
    const float* __restrict__ vars,
    const unsigned short* __restrict__ negWt, const float* __restrict__ negb,
    const unsigned short* __restrict__ W1t, const float* __restrict__ b1,
    const unsigned short* __restrict__ W2t, const float* __restrict__ b2,
    unsigned char* __restrict__ t_pos8, unsigned char* __restrict__ t_neg8) {
  __shared__ unsigned short xs[32][136];
  __shared__ unsigned short ys[32][136];
  __shared__ float ssp[32][4];
  const int tid = threadIdx.x;
  const int wave = tid >> 6, lane = tid & 63;
  const int lan15 = lane & 15, kq = lane >> 4;
  const long vb = (long)blockIdx.x * 32;

  stage_f32_32(vars, vb, V_N, xs, tid);
  __syncthreads();

  float nb[2], bb1[2], bb2[2];
#pragma unroll
  for (int ct = 0; ct < 2; ++ct) {
    int col = wave * 32 + ct * 16 + lan15;
    nb[ct] = negb[col]; bb1[ct] = b1[col]; bb2[ct] = b2[col];
  }
  // ys = xs@negW + negb
  {
    short8 BN[2][4];
    load_bfrags(negWt, BN, wave, lane);
    f32x4 acc[2][2];
    zero_acc2(acc);
    gemm_reg32(xs, BN, acc, lane);
#pragma unroll
    for (int rt = 0; rt < 2; ++rt)
#pragma unroll
      for (int ct = 0; ct < 2; ++ct) {
        int col = wave * 32 + ct * 16 + lan15;
#pragma unroll
        for (int reg = 0; reg < 4; ++reg)
          ys[rt * 16 + kq * 4 + reg][col] = f2bf(acc[rt][ct][reg] + nb[ct]);
      }
  }
  __syncthreads();

  short8 B1f[2][4], B2f[2][4];
  load_bfrags(W1t, B1f, wave, lane);
  load_bfrags(W2t, B2f, wave, lane);

#pragma unroll
  for (int pass = 0; pass < 2; ++pass) {
    const unsigned short (*A)[136] = pass ? ys : xs;
    unsigned char* dst8 = pass ? t_neg8 : t_pos8;
    f32x4 a1[2][2], a2[2][2];
    zero_acc2(a1); zero_acc2(a2);
    gemm_reg32(A, B1f, a1, lane);
    gemm_reg32(A, B2f, a2, lane);
    float s[2][2][4]; float ss[2][4];
#pragma unroll
    for (int rt = 0; rt < 2; ++rt) {
#pragma unroll
      for (int reg = 0; reg < 4; ++reg) ss[rt][reg] = 0.f;
#pragma unroll
      for (int ct = 0; ct < 2; ++ct)
#pragma unroll
        for (int reg = 0; reg < 4; ++reg) {
          float v = sigm(a1[rt][ct][reg] + bb1[ct]) + (a2[rt][ct][reg] + bb2[ct]);
          s[rt][ct][reg] = v; ss[rt][reg] += v * v;
        }
    }
#pragma unroll
    for (int rt = 0; rt < 2; ++rt)
#pragma unroll
      for (int reg = 0; reg < 4; ++reg) {
        float v = ss[rt][reg];
        v += __shfl_xor(v, 1); v += __shfl_xor(v, 2);
        v += __shfl_xor(v, 4); v += __shfl_xor(v, 8);
        if (lan15 == 0) ssp[rt * 16 + kq * 4 + reg][wave] = v;
      }
    __syncthreads();
#pragma unroll
    for (int rt = 0; rt < 2; ++rt)
#pragma unroll
      for (int reg = 0; reg < 4; ++reg) {
        int row = rt * 16 + kq * 4 + reg;
        float tot = ssp[row][0] + ssp[row][1] + ssp[row][2] + ssp[row][3];
        float inv = 1.f / fmaxf(sqrtf(tot), 1e-12f);
        long vr = vb + row;
        if (vr < V_N) {
#pragma unroll
          for (int ct = 0; ct < 2; ++ct)
            dst8[vr * 128 + wave * 32 + ct * 16 + lan15] =
                f2e4m3(s[rt][ct][reg] * inv);
        }
      }
    __syncthreads();
  }
}

__global__ __launch_bounds__(256) void k_scan_pre(const int* __restrict__ cnt,
                                                  int* __restrict__ bsum) {
  __shared__ int sh[256];
  const int tid = threadIdx.x;
  int i = blockIdx.x * 256 + tid;
  int v = (i < V_N) ? cnt[i] : 0;
  sh[tid] = v;
  __syncthreads();
  for (int off = 1; off < 256; off <<= 1) {
    int add = (tid >= off) ? sh[tid - off] : 0;
    __syncthreads();
    sh[tid] += add;
    __syncthreads();
  }
  if (tid == 255) bsum[blockIdx.x] = sh[255];
}

// fused mid+post: each block locally scans bsum (raw per-block totals)
__global__ __launch_bounds__(256) void k_scan_post(const int* __restrict__ cnt,
                                                   const int* __restrict__ bsum,
                                                   int* __restrict__ col_start,
                                                   int nb) {
  __shared__ int sh[256];
  __shared__ int shb[256];
  const int tid = threadIdx.x;
  int bv = (tid < nb) ? bsum[tid] : 0;
  shb[tid] = bv;
  __syncthreads();
  for (int off = 1; off < 256; off <<= 1) {
    int add = (tid >= off) ? shb[tid - off] : 0;
    __syncthreads();
    shb[tid] += add;
    __syncthreads();
  }
  int bpref = (blockIdx.x == 0) ? 0 : shb[blockIdx.x - 1];
  int i = blockIdx.x * 256 + tid;
  int v = (i < V_N) ? cnt[i] : 0;
  sh[tid] = v;
  __syncthreads();
  for (int off = 1; off < 256; off <<= 1) {
    int add = (tid >= off) ? sh[tid - off] : 0;
    __syncthreads();
    sh[tid] += add;
    __syncthreads();
  }
  if (i < V_N) col_start[i + 1] = sh[tid] + bpref;
  if (i == 0) col_start[0] = 0;
}

// Phase 1b+2 fused: per block = 32 clauses, per wave = 8 clauses.
// Literal segment-sum on the MFMA pipe via fp8 (e4m3) tables — rows are
// 128 B (2 cache lines) instead of 256 B, halving random L2-miss lines.
//   CE[8 clauses(+8 unused)][16 cols] += onehotA[16][32 lits] @ T8[32][16]
// fp8 MFMA: A,B are i64 (8 bytes = 8 k-elems per lane); A and B are both
// packed with the SAME byte->k convention so any HW permutation cancels.
// Then 32-row bf16 combine-GEMM, store to crows[dst[c]+col_start[cv[c]]].
__global__ __launch_bounds__(256, 4) void k_sc_clause(
    const int* __restrict__ pmeta, const int* __restrict__ bnd,
    const unsigned char* __restrict__ t_pos8,
    const unsigned char* __restrict__ t_neg8,
    const int* __restrict__ dst, const int* __restrict__ col_start,
    const int* __restrict__ clause_var,
    const unsigned short* __restrict__ W1t, const float* __restrict__ b1,
    const unsigned short* __restrict__ W2t, const float* __restrict__ b2,
    unsigned short* __restrict__ crows) {
  __shared__ unsigned short xs[32][136];
  __shared__ float ssp[32][4];
  __shared__ int dsts[32];
  const int tid = threadIdx.x;
  const int wave = tid >> 6, lane = tid & 63;
  const int lan15 = lane & 15, kq = lane >> 4;
  const int cb = blockIdx.x * 32;

  if (tid < 32) {
    int c = cb + tid;
    dsts[tid] = (c < C_N) ? dst[c] + col_start[clause_var[c]] : -1;
  }

  // wave's clauses: [cb+8*wave, cb+8*wave+8) = 2 bnd units of 4 clauses
  int bi0 = blockIdx.x * 8 + wave * 2;
  int i0 = bi0 < NCH2 ? bi0 : NCH2;
  int i1 = (bi0 + 2) < NCH2 ? (bi0 + 2) : NCH2;
  int ws = bnd[i0], we = bnd[i1];

  f32x4 acc[8];
#pragma unroll
  for (int s = 0; s < 8; ++s) acc[s] = (f32x4)(0.f);

  const int mtarget = (lan15 < 8) ? ((cb & 63) + wave * 8 + lan15) : 127;

  for (int base = ws; base < we; base += 32) {
    // metas for this 32-literal batch (sentinel rc=126 matches no row)
    int mm = 0x00FC0000;
    if (lane < 32) {
      int idx = base + lane;
      if (idx < we) mm = pmeta[idx];
    }
    // B gathers: t8[e][s] = T8[var(8kq+e)][s*16 + lan15], 64 byte loads
    unsigned t8[8][8];
#pragma unroll
    for (int e = 0; e < 8; ++e) {
      int mv = __shfl(mm, 8 * kq + e);
      int v = mv & 0xFFFF;
      const unsigned char* rp =
          ((mv & 0x10000) ? t_neg8 : t_pos8) + (long)v * 128 + lan15;
#pragma unroll
      for (int s = 0; s < 8; ++s) t8[e][s] = rp[s * 16];
    }
    // one-hot A in fp8: byte e = 0x38 (1.0 e4m3) if literal 8kq+e matches
    unsigned a0 = 0, a1 = 0;
#pragma unroll
    for (int e = 0; e < 4; ++e) {
      int m0 = __shfl(mm, 8 * kq + e);
      if (((m0 >> 17) & 127) == mtarget) a0 |= 0x38u << (8 * e);
      int m1 = __shfl(mm, 8 * kq + 4 + e);
      if (((m1 >> 17) & 127) == mtarget) a1 |= 0x38u << (8 * e);
    }
    union { unsigned u[2]; long long ll; } ua;
    ua.u[0] = a0; ua.u[1] = a1;
#pragma unroll
    for (int s = 0; s < 8; ++s) {
      union { unsigned u[2]; long long ll; } ub;
      ub.u[0] = t8[0][s] | (t8[1][s] << 8) | (t8[2][s] << 16) | (t8[3][s] << 24);
      ub.u[1] = t8[4][s] | (t8[5][s] << 8) | (t8[6][s] << 16) | (t8[7][s] << 24);
      acc[s] = __builtin_amdgcn_mfma_f32_16x16x32_fp8_fp8(ua.ll, ub.ll, acc[s], 0, 0, 0);
    }
  }

  // C layout (m89-verified, dtype-independent): row = 4*kq+reg, col = lan15.
  // Only rows 0..7 (kq<2) are real clauses of this wave.
  if (kq < 2) {
#pragma unroll
    for (int s = 0; s < 8; ++s)
#pragma unroll
      for (int reg = 0; reg < 4; ++reg)
        xs[wave * 8 + 4 * kq + reg][s * 16 + lan15] = f2bf(acc[s][reg]);
  }
  __syncthreads();

  // combine-GEMM on xs (32 rows), store to crows[dsts]
  short8 B1f[2][4], B2f[2][4];
  load_bfrags(W1t, B1f, wave, lane);
  load_bfrags(W2t, B2f, wave, lane);
  float bb1[2], bb2[2];
#pragma unroll
  for (int ct = 0; ct < 2; ++ct) {
    int col = wave * 32 + ct * 16 + lan15;
    bb1[ct] = b1[col]; bb2[ct] = b2[col];
  }
  f32x4 a1[2][2], a2[2][2];
  zero_acc2(a1); zero_acc2(a2);
  gemm_reg32(xs, B1f, a1, lane);
  gemm_reg32(xs, B2f, a2, lane);
  float s[2][2][4]; float ss[2][4];
#pragma unroll
  for (int rt = 0; rt < 2; ++rt) {
#pragma unroll
    for (int reg = 0; reg < 4; ++reg) ss[rt][reg] = 0.f;
#pragma unroll
    for (int ct = 0; ct < 2; ++ct)
#pragma unroll
      for (int reg = 0; reg < 4; ++reg) {
        float v = sigm(a1[rt][ct][reg] + bb1[ct]) + (a2[rt][ct][reg] + bb2[ct]);
        s[rt][ct][reg] = v; ss[rt][reg] += v * v;
      }
  }
#pragma unroll
  for (int rt = 0; rt < 2; ++rt)
#pragma unroll
    for (int reg = 0; reg < 4; ++reg) {
      float v = ss[rt][reg];
      v += __shfl_xor(v, 1); v += __shfl_xor(v, 2);
      v += __shfl_xor(v, 4); v += __shfl_xor(v, 8);
      if (lan15 == 0) ssp[rt * 16 + kq * 4 + reg][wave] = v;
    }
  __syncthreads();
#pragma unroll
  for (int rt = 0; rt < 2; ++rt)
#pragma unroll
    for (int reg = 0; reg < 4; ++reg) {
      int row = rt * 16 + kq * 4 + reg;
      float tot = ssp[row][0] + ssp[row][1] + ssp[row][2] + ssp[row][3];
      float inv = 1.f / fmaxf(sqrtf(tot), 1e-12f);
      int dd = dsts[row];
      if (dd >= 0) {
#pragma unroll
        for (int ct = 0; ct < 2; ++ct)
          crows[(long)dd * 128 + wave * 32 + ct * 16 + lan15] =
              f2bf(s[rt][ct][reg] * inv);
      }
    }
}

// Phase 3 fused GRU: 32-row tiles for parallelism (grid ~1563 blocks)
__global__ __launch_bounds__(256, 2) void k_gru(
    const float* __restrict__ vars,
    const unsigned short* __restrict__ crows, const int* __restrict__ col_start,
    const unsigned short* __restrict__ Wzt, const unsigned short* __restrict__ Uzt,
    const unsigned short* __restrict__ Wrt, const unsigned short* __restrict__ Urt,
    const unsigned short* __restrict__ Wht, const unsigned short* __restrict__ Uht,
    float* __restrict__ out) {
  __shared__ unsigned short as_[32][136];
  __shared__ unsigned short vs[32][136];
  const int tid = threadIdx.x;
  const int wave = tid >> 6, lane = tid & 63;
  const int lan15 = lane & 15, kq = lane >> 4;
  const long vb = (long)blockIdx.x * 32;

  // gather av -> as_  (16 cols/thread)
  {
    int r = tid >> 3, cq = (tid & 7) * 16;
    long v = vb + r;
    if (v < V_N) {
      int s0 = col_start[v], s1 = col_start[v + 1];
      if (s1 > s0) {
        float acc[16];
#pragma unroll
        for (int j = 0; j < 16; ++j) acc[j] = 0.f;
        for (int t = s0; t < s1; ++t) {
          const unsigned short* rp = crows + (long)t * 128 + cq;
#pragma unroll
          for (int j = 0; j < 16; j += 8) {
            short8 u = *(const short8*)(rp + j);
#pragma unroll
            for (int e = 0; e < 8; ++e) acc[j + e] += bf2f((unsigned short)u[e]);
          }
        }
#pragma unroll
        for (int j = 0; j < 16; ++j) as_[r][cq + j] = f2bf(acc[j]);
      } else {
#pragma unroll
        for (int j = 0; j < 16; j += 4) {
          float4 x4 = *(const float4*)(vars + v * 128 + cq + j);
          as_[r][cq + j + 0] = f2bf(x4.x);
          as_[r][cq + j + 1] = f2bf(x4.y);
          as_[r][cq + j + 2] = f2bf(x4.z);
          as_[r][cq + j + 3] = f2bf(x4.w);
        }
      }
    } else {
#pragma unroll
      for (int j = 0; j < 16; ++j) as_[r][cq + j] = 0;
    }
  }
  stage_f32_32(vars, vb, V_N, vs, tid);
  __syncthreads();

  f32x4 az[2][2];
  zero_acc2(az);
  {
    short8 BA[2][4], BB[2][4];
    load_bfrags(Wzt, BA, wave, lane);
    load_bfrags(Uzt, BB, wave, lane);
    gemm_reg32(as_, BA, az, lane);
    gemm_reg32(vs, BB, az, lane);
  }
  f32x4 ar[2][2];
  zero_acc2(ar);
  {
    short8 BA[2][4], BB[2][4];
    load_bfrags(Wrt, BA, wave, lane);
    load_bfrags(Urt, BB, wave, lane);
    gemm_reg32(as_, BA, ar, lane);
    gemm_reg32(vs, BB, ar, lane);
  }
  __syncthreads();
#pragma unroll
  for (int rt = 0; rt < 2; ++rt)
#pragma unroll
    for (int ct = 0; ct < 2; ++ct) {
      int col = wave * 32 + ct * 16 + lan15;
#pragma unroll
      for (int reg = 0; reg < 4; ++reg) {
        int row = rt * 16 + kq * 4 + reg;
        float rr = sigm(ar[rt][ct][reg]);
        float vf = bf2f(vs[row][col]);
        vs[row][col] = f2bf(rr * vf);
      }
    }
  __syncthreads();
  f32x4 ah[2][2];
  zero_acc2(ah);
  {
    short8 BA[2][4], BB[2][4];
    load_bfrags(Wht, BA, wave, lane);
    load_bfrags(Uht, BB, wave, lane);
    gemm_reg32(as_, BA, ah, lane);
    gemm_reg32(vs, BB, ah, lane);
  }
#pragma unroll
  for (int rt = 0; rt < 2; ++rt)
#pragma unroll
    for (int ct = 0; ct < 2; ++ct) {
      int col = wave * 32 + ct * 16 + lan15;
#pragma unroll
      for (int reg = 0; reg < 4; ++reg) {
        int row = rt * 16 + kq * 4 + reg;
        long v = vb + row;
        if (v < V_N) {
          float z = sigm(az[rt][ct][reg]);
          float h = tanhf(ah[rt][ct][reg]);
          float vf = vars[v * 128 + col];
          out[v * 128 + col] = (1.f - z) * vf + z * h;
        }
      }
    }
}

extern "C" void kernel_launch(void* const* d_in, const int* in_sizes, int n_in,
                              void* d_out, int out_size, void* d_ws, size_t ws_size,
                              hipStream_t stream) {
  const float* vars = (const float*)d_in[0];
  const int* lit_var = (const int*)d_in[1];
  const int* lit_sign = (const int*)d_in[2];
  const int* lit_clause = (const int*)d_in[3];
  const int* clause_var = (const int*)d_in[4];
  const float* negW = (const float*)d_in[5];
  const float* negb = (const float*)d_in[6];
  const float* vcW1 = (const float*)d_in[7];
  const float* vcb1 = (const float*)d_in[8];
  const float* vcW2 = (const float*)d_in[9];
  const float* vcb2 = (const float*)d_in[10];
  const float* ccW1 = (const float*)d_in[11];
  const float* ccb1 = (const float*)d_in[12];
  const float* ccW2 = (const float*)d_in[13];
  const float* ccb2 = (const float*)d_in[14];
  const float* Wz = (const float*)d_in[15];
  const float* Uz = (const float*)d_in[16];
  const float* Wr = (const float*)d_in[17];
  const float* Ur = (const float*)d_in[18];
  const float* Wh = (const float*)d_in[19];
  const float* Uh = (const float*)d_in[20];

  // workspace layout (~61.5 MB reserved):
  //   [0, 360448)              wt: 11 x 128x128 bf16 W^T (fragment-ordered)
  //   [360448, 6760448)        t_pos8 fp8 e4m3 (V_N x 128)
  //   [6760448, 13160448)      t_neg8 fp8 e4m3
  //   [25960448, 57960448)     crows bf16
  //   [58000000, 58200004)     col_start (V_N+1)
  //   [58300000, 58500000)     cnt
  //   [58600000, 59100000)     dst
  //   [59200000, 59200784)     bsum
  //   [59300000, 59425004)     bnd (NCH2+1 ints)
  //   [59500000, 61500000)     pmeta (L_N ints)
  unsigned char* ws = (unsigned char*)d_ws;
  unsigned short* wt = (unsigned short*)ws;
  unsigned char* t_pos8 = ws + 360448;
  unsigned char* t_neg8 = ws + 6760448;
  unsigned short* crows = (unsigned short*)(ws + 25960448);
  int* col_start = (int*)(ws + 58000000);
  int* cnt = (int*)(ws + 58300000);
  int* dst = (int*)(ws + 58600000);
  int* bsum = (int*)(ws + 59200000);
  int* bnd = (int*)(ws + 59300000);
  int* pmeta = (int*)(ws + 59500000);
  if (ws_size < (size_t)61500000) return;

  const int NB = (V_N + 255) / 256;  // 196 scan blocks

  WPtrs p;
  p.w[0] = negW; p.w[1] = vcW1; p.w[2] = vcW2; p.w[3] = ccW1; p.w[4] = ccW2;
  p.w[5] = Wz; p.w[6] = Uz; p.w[7] = Wr; p.w[8] = Ur; p.w[9] = Wh; p.w[10] = Uh;

  hipMemsetAsync(ws + 58300000, 0, (size_t)200000, stream);  // cnt
  // fused prep + meta + bnd + hist (hist needs cnt zeroed by the memset)
  hipLaunchKernelGGL(k_front, dim3(3270), dim3(256), 0, stream, p, wt,
                     lit_var, lit_sign, lit_clause, pmeta, bnd, clause_var,
                     cnt, dst);

  hipLaunchKernelGGL(k_scan_pre, dim3(NB), dim3(256), 0, stream, cnt, bsum);
  hipLaunchKernelGGL(k_scan_post, dim3(NB), dim3(256), 0, stream, cnt, bsum,
                     col_start, NB);

  hipLaunchKernelGGL(k_tables, dim3((V_N + 31) / 32), dim3(256), 0, stream,
                     vars, wt + 0, negb, wt + 16384, vcb1, wt + 2 * 16384, vcb2,
                     t_pos8, t_neg8);

  hipLaunchKernelGGL(k_sc_clause, dim3((C_N + 31) / 32), dim3(256), 0, stream,
                     pmeta, bnd, t_pos8, t_neg8, dst, col_start, clause_var,
                     wt + 3 * 16384, ccb1, wt + 4 * 16384, ccb2, crows);

  hipLaunchKernelGGL(k_gru, dim3((V_N + 31) / 32), dim3(256), 0, stream,
                     vars, crows, col_start,
                     wt + 5 * 16384, wt + 6 * 16384, wt + 7 * 16384,
                     wt + 8 * 16384, wt + 9 * 16384, wt + 10 * 16384,
                     (float*)d_out);
}

// Round 15
// 139.525 us; speedup vs baseline: 1.0723x; 1.0723x over previous
//
#include <hip/hip_runtime.h>

#define V_N 50000
#define C_N 125000
#define L_N 500000
#define NCH2 31250  // C_N/4 sub-chains of 4 clauses
// D = 128

typedef __attribute__((ext_vector_type(8))) short short8;
typedef __attribute__((ext_vector_type(4))) float f32x4;

__device__ inline unsigned short f2bf(float f) {
  union { float f; unsigned u; } v; v.f = f;
  unsigned r = v.u + 0x7FFFu + ((v.u >> 16) & 1u);
  return (unsigned short)(r >> 16);
}
__device__ inline float bf2f(unsigned short h) {
  union { unsigned u; float f; } v; v.u = ((unsigned)h) << 16;
  return v.f;
}
__device__ inline float sigm(float x) { return 1.f / (1.f + __expf(-x)); }

struct WPtrs { const float* w[11]; };

// Fused front kernel: block-range dispatch of
//   [0,704)            k_prep: 11 weights -> fragment-ordered bf16 layout
//   [704,2658)         k_meta: pmeta[i] = var | sign<<16 | (clause&63)<<17
//   [2658,2781)        k_bnd:  bnd[i] = lower_bound(lit_clause, i*4)
//   [2781,3270)        k_hist: dst[i] = atomicAdd(&cnt[clause_var[i]],1)
__global__ __launch_bounds__(256) void k_front(
    WPtrs p, unsigned short* __restrict__ wt,
    const int* __restrict__ lit_var, const int* __restrict__ lit_sign,
    const int* __restrict__ lit_clause, int* __restrict__ pmeta,
    int* __restrict__ bnd, const int* __restrict__ clause_var,
    int* __restrict__ cnt, int* __restrict__ dst) {
  int b = blockIdx.x;
  if (b < 704) {
    int idx = b * 256 + threadIdx.x;  // 11*16384 total, exact
    int m = idx >> 14;
    int j = idx & 16383;          // input-linear: j = k*128 + col
    int k = j >> 7, col = j & 127;
    float val = p.w[m][j];        // coalesced read
    int chunk = ((col >> 5) << 3) + (((col >> 4) & 1) << 2) + (k >> 5);
    int off = (((k >> 3) & 3) << 7) + ((col & 15) << 3) + (k & 7);
    wt[m * 16384 + chunk * 512 + off] = f2bf(val);
  } else if (b < 2658) {
    int i = (b - 704) * 256 + threadIdx.x;
    if (i < L_N)
      pmeta[i] = lit_var[i] | (lit_sign[i] << 16) | ((lit_clause[i] & 63) << 17);
  } else if (b < 2781) {
    int i = (b - 2658) * 256 + threadIdx.x;
    if (i <= NCH2) {
      int key = i * 4;
      int lo = 0, hi = L_N;
      while (lo < hi) {
        int mid = (lo + hi) >> 1;
        if (lit_clause[mid] < key) lo = mid + 1; else hi = mid;
      }
      bnd[i] = lo;
    }
  } else {
    int i = (b - 2781) * 256 + threadIdx.x;
    if (i < C_N) {
      int v = clause_var[i];
      dst[i] = atomicAdd(&cnt[v], 1);
    }
  }
}

// ---- register-resident B fragments: wave tile = N rows x 32 cols ----
__device__ inline void load_bfrags(const unsigned short* __restrict__ Wt,
                                   short8 B[2][4], int wave, int lane) {
#pragma unroll
  for (int ct = 0; ct < 2; ++ct)
#pragma unroll
    for (int ks = 0; ks < 4; ++ks)
      B[ct][ks] = *(const short8*)(Wt + (((wave << 3) + (ct << 2) + ks) << 9) +
                                   (lane << 3));
}

// 32-row tile GEMM (k_tables / k_gru / k_sc_clause epilogue)
__device__ inline void gemm_reg32(const unsigned short (*__restrict__ xs)[136],
                                  const short8 B[2][4], f32x4 acc[2][2], int lane) {
  const int lan15 = lane & 15, kq = lane >> 4;
#pragma unroll
  for (int ks = 0; ks < 4; ++ks) {
#pragma unroll
    for (int rt = 0; rt < 2; ++rt) {
      short8 a = *(const short8*)(&xs[rt * 16 + lan15][ks * 32 + kq * 8]);
#pragma unroll
      for (int ct = 0; ct < 2; ++ct)
        acc[rt][ct] = __builtin_amdgcn_mfma_f32_16x16x32_bf16(a, B[ct][ks], acc[rt][ct], 0, 0, 0);
    }
  }
}

__device__ inline void zero_acc2(f32x4 acc[2][2]) {
#pragma unroll
  for (int rt = 0; rt < 2; ++rt)
#pragma unroll
    for (int ct = 0; ct < 2; ++ct) acc[rt][ct] = (f32x4)(0.f);
}

// stage 32 f32 rows -> bf16 LDS tile (zero-pad past nrows); 16 cols/thread
__device__ inline void stage_f32_32(const float* __restrict__ base, long vb, int nrows,
                                    unsigned short (*__restrict__ dst)[136], int tid) {
  int r = tid >> 3, cq = (tid & 7) * 16;
  long v = vb + r;
  bool valid = v < nrows;
  const float* src = valid ? base + v * 128 : base;
#pragma unroll
  for (int j = 0; j < 16; j += 4) {
    float4 x4 = *(const float4*)(src + cq + j);
    if (!valid) { x4.x = 0.f; x4.y = 0.f; x4.z = 0.f; x4.w = 0.f; }
    dst[r][cq + j + 0] = f2bf(x4.x);
    dst[r][cq + j + 1] = f2bf(x4.y);
    dst[r][cq + j + 2] = f2bf(x4.z);
    dst[r][cq + j + 3] = f2bf(x4.w);
  }
}

// Phase 1a: t_pos[v] = combine(vars[v]); t_neg[v] = combine(vars[v]@negW+negb)
__global__ __launch_bounds__(256, 2) void k_tables(
    const float* __restrict__ vars,
    const unsigned short* __restrict__ negWt, const float* __restrict__ negb,
    const unsigned short* __restrict__ W1t, const float* __restrict__ b1,
    const unsigned short* __restrict__ W2t, const float* __restrict__ b2,
    unsigned short* __restrict__ t_pos, unsigned short* __restrict__ t_neg) {
  __shared__ unsigned short xs[32][136];
  __shared__ unsigned short ys[32][136];
  __shared__ float ssp[32][4];
  const int tid = threadIdx.x;
  const int wave = tid >> 6, lane = tid & 63;
  const int lan15 = lane & 15, kq = lane >> 4;
  const long vb = (long)blockIdx.x * 32;

  stage_f32_32(vars, vb, V_N, xs, tid);
  __syncthreads();

  float nb[2], bb1[2], bb2[2];
#pragma unroll
  for (int ct = 0; ct < 2; ++ct) {
    int col = wave * 32 + ct * 16 + lan15;
    nb[ct] = negb[col]; bb1[ct] = b1[col]; bb2[ct] = b2[col];
  }
  // ys = xs@negW + negb
  {
    short8 BN[2][4];
    load_bfrags(negWt, BN, wave, lane);
    f32x4 acc[2][2];
    zero_acc2(acc);
    gemm_reg32(xs, BN, acc, lane);
#pragma unroll
    for (int rt = 0; rt < 2; ++rt)
#pragma unroll
      for (int ct = 0; ct < 2; ++ct) {
        int col = wave * 32 + ct * 16 + lan15;
#pragma unroll
        for (int reg = 0; reg < 4; ++reg)
          ys[rt * 16 + kq * 4 + reg][col] = f2bf(acc[rt][ct][reg] + nb[ct]);
      }
  }
  __syncthreads();

  short8 B1f[2][4], B2f[2][4];
  load_bfrags(W1t, B1f, wave, lane);
  load_bfrags(W2t, B2f, wave, lane);

#pragma unroll
  for (int pass = 0; pass < 2; ++pass) {
    const unsigned short (*A)[136] = pass ? ys : xs;
    unsigned short* dst = pass ? t_neg : t_pos;
    f32x4 a1[2][2], a2[2][2];
    zero_acc2(a1); zero_acc2(a2);
    gemm_reg32(A, B1f, a1, lane);
    gemm_reg32(A, B2f, a2, lane);
    float s[2][2][4]; float ss[2][4];
#pragma unroll
    for (int rt = 0; rt < 2; ++rt) {
#pragma unroll
      for (int reg = 0; reg < 4; ++reg) ss[rt][reg] = 0.f;
#pragma unroll
      for (int ct = 0; ct < 2; ++ct)
#pragma unroll
        for (int reg = 0; reg < 4; ++reg) {
          float v = sigm(a1[rt][ct][reg] + bb1[ct]) + (a2[rt][ct][reg] + bb2[ct]);
          s[rt][ct][reg] = v; ss[rt][reg] += v * v;
        }
    }
#pragma unroll
    for (int rt = 0; rt < 2; ++rt)
#pragma unroll
      for (int reg = 0; reg < 4; ++reg) {
        float v = ss[rt][reg];
        v += __shfl_xor(v, 1); v += __shfl_xor(v, 2);
        v += __shfl_xor(v, 4); v += __shfl_xor(v, 8);
        if (lan15 == 0) ssp[rt * 16 + kq * 4 + reg][wave] = v;
      }
    __syncthreads();
#pragma unroll
    for (int rt = 0; rt < 2; ++rt)
#pragma unroll
      for (int reg = 0; reg < 4; ++reg) {
        int row = rt * 16 + kq * 4 + reg;
        float tot = ssp[row][0] + ssp[row][1] + ssp[row][2] + ssp[row][3];
        float inv = 1.f / fmaxf(sqrtf(tot), 1e-12f);
        long vr = vb + row;
        if (vr < V_N) {
#pragma unroll
          for (int ct = 0; ct < 2; ++ct)
            dst[vr * 128 + wave * 32 + ct * 16 + lan15] = f2bf(s[rt][ct][reg] * inv);
        }
      }
    __syncthreads();
  }
}

__global__ __launch_bounds__(256) void k_scan_pre(const int* __restrict__ cnt,
                                                  int* __restrict__ bsum) {
  __shared__ int sh[256];
  const int tid = threadIdx.x;
  int i = blockIdx.x * 256 + tid;
  int v = (i < V_N) ? cnt[i] : 0;
  sh[tid] = v;
  __syncthreads();
  for (int off = 1; off < 256; off <<= 1) {
    int add = (tid >= off) ? sh[tid - off] : 0;
    __syncthreads();
    sh[tid] += add;
    __syncthreads();
  }
  if (tid == 255) bsum[blockIdx.x] = sh[255];
}

// fused mid+post: each block locally scans bsum (raw per-block totals)
__global__ __launch_bounds__(256) void k_scan_post(const int* __restrict__ cnt,
                                                   const int* __restrict__ bsum,
                                                   int* __restrict__ col_start,
                                                   int nb) {
  __shared__ int sh[256];
  __shared__ int shb[256];
  const int tid = threadIdx.x;
  int bv = (tid < nb) ? bsum[tid] : 0;
  shb[tid] = bv;
  __syncthreads();
  for (int off = 1; off < 256; off <<= 1) {
    int add = (tid >= off) ? shb[tid - off] : 0;
    __syncthreads();
    shb[tid] += add;
    __syncthreads();
  }
  int bpref = (blockIdx.x == 0) ? 0 : shb[blockIdx.x - 1];
  int i = blockIdx.x * 256 + tid;
  int v = (i < V_N) ? cnt[i] : 0;
  sh[tid] = v;
  __syncthreads();
  for (int off = 1; off < 256; off <<= 1) {
    int add = (tid >= off) ? sh[tid - off] : 0;
    __syncthreads();
    sh[tid] += add;
    __syncthreads();
  }
  if (i < V_N) col_start[i + 1] = sh[tid] + bpref;
  if (i == 0) col_start[0] = 0;
}

// Phase 1b+2 fused: per block = 32 clauses, per wave = 8 clauses.
// Literal segment-sum on the MFMA pipe with STANDARD fragment layouts:
//   CE[8 clauses(+8 unused)][16 cols] += onehotA[16][32 lits] @ T[32][16]
// B: lane(n=lan15,kq) elem e = T[var(lit 8kq+e)][s*16+n], plain loads.
// Then 32-row combine-GEMM, store to crows[dst[c]+col_start[cv[c]]].
__global__ __launch_bounds__(256, 4) void k_sc_clause(
    const int* __restrict__ pmeta, const int* __restrict__ bnd,
    const unsigned short* __restrict__ t_pos,
    const unsigned short* __restrict__ t_neg,
    const int* __restrict__ dst, const int* __restrict__ col_start,
    const int* __restrict__ clause_var,
    const unsigned short* __restrict__ W1t, const float* __restrict__ b1,
    const unsigned short* __restrict__ W2t, const float* __restrict__ b2,
    unsigned short* __restrict__ crows) {
  __shared__ unsigned short xs[32][136];
  __shared__ float ssp[32][4];
  __shared__ int dsts[32];
  const int tid = threadIdx.x;
  const int wave = tid >> 6, lane = tid & 63;
  const int lan15 = lane & 15, kq = lane >> 4;
  const int cb = blockIdx.x * 32;

  if (tid < 32) {
    int c = cb + tid;
    dsts[tid] = (c < C_N) ? dst[c] + col_start[clause_var[c]] : -1;
  }

  // wave's clauses: [cb+8*wave, cb+8*wave+8) = 2 bnd units of 4 clauses
  int bi0 = blockIdx.x * 8 + wave * 2;
  int i0 = bi0 < NCH2 ? bi0 : NCH2;
  int i1 = (bi0 + 2) < NCH2 ? (bi0 + 2) : NCH2;
  int ws = bnd[i0], we = bnd[i1];

  f32x4 acc[8];
#pragma unroll
  for (int s = 0; s < 8; ++s) acc[s] = (f32x4)(0.f);

  const int mtarget = (lan15 < 8) ? ((cb & 63) + wave * 8 + lan15) : 127;

  for (int base = ws; base < we; base += 32) {
    // metas for this 32-literal batch (sentinel rc=126 matches no row)
    int mm = 0x00FC0000;
    if (lane < 32) {
      int idx = base + lane;
      if (idx < we) mm = pmeta[idx];
    }
    // one-hot A fragment: elem pair pp <-> literals k=8kq+2pp, +1
    unsigned au[4];
#pragma unroll
    for (int pp = 0; pp < 4; ++pp) {
      int m0 = __shfl(mm, 8 * kq + 2 * pp);
      int m1 = __shfl(mm, 8 * kq + 2 * pp + 1);
      unsigned lo = (((m0 >> 17) & 127) == mtarget) ? 0x3F80u : 0u;
      unsigned hi = (((m1 >> 17) & 127) == mtarget) ? 0x3F800000u : 0u;
      au[pp] = lo | hi;
    }
    // B gathers: t16[e][s] = T[var(8kq+e)][s*16 + lan15], 64 indep loads
    unsigned t16[8][8];
#pragma unroll
    for (int e = 0; e < 8; ++e) {
      int mv = __shfl(mm, 8 * kq + e);
      int v = mv & 0xFFFF;
      const unsigned short* rp =
          ((mv & 0x10000) ? t_neg : t_pos) + (long)v * 128 + lan15;
#pragma unroll
      for (int s = 0; s < 8; ++s) t16[e][s] = rp[s * 16];
    }
    union { unsigned u[4]; short8 s8; } ua;
    ua.u[0] = au[0]; ua.u[1] = au[1]; ua.u[2] = au[2]; ua.u[3] = au[3];
#pragma unroll
    for (int s = 0; s < 8; ++s) {
      union { unsigned u[4]; short8 s8; } ub;
#pragma unroll
      for (int d = 0; d < 4; ++d)
        ub.u[d] = t16[2 * d][s] | (t16[2 * d + 1][s] << 16);
      acc[s] = __builtin_amdgcn_mfma_f32_16x16x32_bf16(ua.s8, ub.s8, acc[s], 0, 0, 0);
    }
  }

  // C layout (m89-verified): row = 4*kq + reg, col = lan15 (per slice s).
  // Only rows 0..7 (kq<2) are real clauses of this wave.
  if (kq < 2) {
#pragma unroll
    for (int s = 0; s < 8; ++s)
#pragma unroll
      for (int reg = 0; reg < 4; ++reg)
        xs[wave * 8 + 4 * kq + reg][s * 16 + lan15] = f2bf(acc[s][reg]);
  }
  __syncthreads();

  // combine-GEMM on xs (32 rows), store to crows[dsts]
  short8 B1f[2][4], B2f[2][4];
  load_bfrags(W1t, B1f, wave, lane);
  load_bfrags(W2t, B2f, wave, lane);
  float bb1[2], bb2[2];
#pragma unroll
  for (int ct = 0; ct < 2; ++ct) {
    int col = wave * 32 + ct * 16 + lan15;
    bb1[ct] = b1[col]; bb2[ct] = b2[col];
  }
  f32x4 a1[2][2], a2[2][2];
  zero_acc2(a1); zero_acc2(a2);
  gemm_reg32(xs, B1f, a1, lane);
  gemm_reg32(xs, B2f, a2, lane);
  float s[2][2][4]; float ss[2][4];
#pragma unroll
  for (int rt = 0; rt < 2; ++rt) {
#pragma unroll
    for (int reg = 0; reg < 4; ++reg) ss[rt][reg] = 0.f;
#pragma unroll
    for (int ct = 0; ct < 2; ++ct)
#pragma unroll
      for (int reg = 0; reg < 4; ++reg) {
        float v = sigm(a1[rt][ct][reg] + bb1[ct]) + (a2[rt][ct][reg] + bb2[ct]);
        s[rt][ct][reg] = v; ss[rt][reg] += v * v;
      }
  }
#pragma unroll
  for (int rt = 0; rt < 2; ++rt)
#pragma unroll
    for (int reg = 0; reg < 4; ++reg) {
      float v = ss[rt][reg];
      v += __shfl_xor(v, 1); v += __shfl_xor(v, 2);
      v += __shfl_xor(v, 4); v += __shfl_xor(v, 8);
      if (lan15 == 0) ssp[rt * 16 + kq * 4 + reg][wave] = v;
    }
  __syncthreads();
#pragma unroll
  for (int rt = 0; rt < 2; ++rt)
#pragma unroll
    for (int reg = 0; reg < 4; ++reg) {
      int row = rt * 16 + kq * 4 + reg;
      float tot = ssp[row][0] + ssp[row][1] + ssp[row][2] + ssp[row][3];
      float inv = 1.f / fmaxf(sqrtf(tot), 1e-12f);
      int dd = dsts[row];
      if (dd >= 0) {
#pragma unroll
        for (int ct = 0; ct < 2; ++ct)
          crows[(long)dd * 128 + wave * 32 + ct * 16 + lan15] =
              f2bf(s[rt][ct][reg] * inv);
      }
    }
}

// Phase 3 fused GRU: 32-row tiles; epilogue reuses vars values captured in
// registers during the r-rescale pass (kills the 3rd 25.6MB vars read).
__global__ __launch_bounds__(256, 2) void k_gru(
    const float* __restrict__ vars,
    const unsigned short* __restrict__ crows, const int* __restrict__ col_start,
    const unsigned short* __restrict__ Wzt, const unsigned short* __restrict__ Uzt,
    const unsigned short* __restrict__ Wrt, const unsigned short* __restrict__ Urt,
    const unsigned short* __restrict__ Wht, const unsigned short* __restrict__ Uht,
    float* __restrict__ out) {
  __shared__ unsigned short as_[32][136];
  __shared__ unsigned short vs[32][136];
  const int tid = threadIdx.x;
  const int wave = tid >> 6, lane = tid & 63;
  const int lan15 = lane & 15, kq = lane >> 4;
  const long vb = (long)blockIdx.x * 32;

  // gather av -> as_  (16 cols/thread)
  {
    int r = tid >> 3, cq = (tid & 7) * 16;
    long v = vb + r;
    if (v < V_N) {
      int s0 = col_start[v], s1 = col_start[v + 1];
      if (s1 > s0) {
        float acc[16];
#pragma unroll
        for (int j = 0; j < 16; ++j) acc[j] = 0.f;
        for (int t = s0; t < s1; ++t) {
          const unsigned short* rp = crows + (long)t * 128 + cq;
#pragma unroll
          for (int j = 0; j < 16; j += 8) {
            short8 u = *(const short8*)(rp + j);
#pragma unroll
            for (int e = 0; e < 8; ++e) acc[j + e] += bf2f((unsigned short)u[e]);
          }
        }
#pragma unroll
        for (int j = 0; j < 16; ++j) as_[r][cq + j] = f2bf(acc[j]);
      } else {
#pragma unroll
        for (int j = 0; j < 16; j += 4) {
          float4 x4 = *(const float4*)(vars + v * 128 + cq + j);
          as_[r][cq + j + 0] = f2bf(x4.x);
          as_[r][cq + j + 1] = f2bf(x4.y);
          as_[r][cq + j + 2] = f2bf(x4.z);
          as_[r][cq + j + 3] = f2bf(x4.w);
        }
      }
    } else {
#pragma unroll
      for (int j = 0; j < 16; ++j) as_[r][cq + j] = 0;
    }
  }
  stage_f32_32(vars, vb, V_N, vs, tid);
  __syncthreads();

  f32x4 az[2][2];
  zero_acc2(az);
  {
    short8 BA[2][4], BB[2][4];
    load_bfrags(Wzt, BA, wave, lane);
    load_bfrags(Uzt, BB, wave, lane);
    gemm_reg32(as_, BA, az, lane);
    gemm_reg32(vs, BB, az, lane);
  }
  f32x4 ar[2][2];
  zero_acc2(ar);
  {
    short8 BA[2][4], BB[2][4];
    load_bfrags(Wrt, BA, wave, lane);
    load_bfrags(Urt, BB, wave, lane);
    gemm_reg32(as_, BA, ar, lane);
    gemm_reg32(vs, BB, ar, lane);
  }
  __syncthreads();
  float vfr[2][2][4];  // vars (bf16-rounded) captured for the epilogue
#pragma unroll
  for (int rt = 0; rt < 2; ++rt)
#pragma unroll
    for (int ct = 0; ct < 2; ++ct) {
      int col = wave * 32 + ct * 16 + lan15;
#pragma unroll
      for (int reg = 0; reg < 4; ++reg) {
        int row = rt * 16 + kq * 4 + reg;
        float rr = sigm(ar[rt][ct][reg]);
        float vf = bf2f(vs[row][col]);
        vfr[rt][ct][reg] = vf;
        vs[row][col] = f2bf(rr * vf);
      }
    }
  __syncthreads();
  f32x4 ah[2][2];
  zero_acc2(ah);
  {
    short8 BA[2][4], BB[2][4];
    load_bfrags(Wht, BA, wave, lane);
    load_bfrags(Uht, BB, wave, lane);
    gemm_reg32(as_, BA, ah, lane);
    gemm_reg32(vs, BB, ah, lane);
  }
#pragma unroll
  for (int rt = 0; rt < 2; ++rt)
#pragma unroll
    for (int ct = 0; ct < 2; ++ct) {
      int col = wave * 32 + ct * 16 + lan15;
#pragma unroll
      for (int reg = 0; reg < 4; ++reg) {
        int row = rt * 16 + kq * 4 + reg;
        long v = vb + row;
        if (v < V_N) {
          float z = sigm(az[rt][ct][reg]);
          float h = tanhf(ah[rt][ct][reg]);
          float vf = vfr[rt][ct][reg];
          out[v * 128 + col] = (1.f - z) * vf + z * h;
        }
      }
    }
}

extern "C" void kernel_launch(void* const* d_in, const int* in_sizes, int n_in,
                              void* d_out, int out_size, void* d_ws, size_t ws_size,
                              hipStream_t stream) {
  const float* vars = (const float*)d_in[0];
  const int* lit_var = (const int*)d_in[1];
  const int* lit_sign = (const int*)d_in[2];
  const int* lit_clause = (const int*)d_in[3];
  const int* clause_var = (const int*)d_in[4];
  const float* negW = (const float*)d_in[5];
  const float* negb = (const float*)d_in[6];
  const float* vcW1 = (const float*)d_in[7];
  const float* vcb1 = (const float*)d_in[8];
  const float* vcW2 = (const float*)d_in[9];
  const float* vcb2 = (const float*)d_in[10];
  const float* ccW1 = (const float*)d_in[11];
  const float* ccb1 = (const float*)d_in[12];
  const float* ccW2 = (const float*)d_in[13];
  const float* ccb2 = (const float*)d_in[14];
  const float* Wz = (const float*)d_in[15];
  const float* Uz = (const float*)d_in[16];
  const float* Wr = (const float*)d_in[17];
  const float* Ur = (const float*)d_in[18];
  const float* Wh = (const float*)d_in[19];
  const float* Uh = (const float*)d_in[20];

  // workspace layout (~61.5 MB used):
  //   [0, 360448)              wt: 11 x 128x128 bf16 W^T (fragment-ordered)
  //   [360448, 13160448)       t_pos bf16
  //   [13160448, 25960448)     t_neg bf16
  //   [25960448, 57960448)     crows bf16
  //   [58000000, 58200004)     col_start (V_N+1)
  //   [58300000, 58500000)     cnt
  //   [58600000, 59100000)     dst
  //   [59200000, 59200784)     bsum
  //   [59300000, 59425004)     bnd (NCH2+1 ints)
  //   [59500000, 61500000)     pmeta (L_N ints)
  unsigned char* ws = (unsigned char*)d_ws;
  unsigned short* wt = (unsigned short*)ws;
  unsigned short* t_pos = (unsigned short*)(ws + 360448);
  unsigned short* t_neg = (unsigned short*)(ws + 13160448);
  unsigned short* crows = (unsigned short*)(ws + 25960448);
  int* col_start = (int*)(ws + 58000000);
  int* cnt = (int*)(ws + 58300000);
  int* dst = (int*)(ws + 58600000);
  int* bsum = (int*)(ws + 59200000);
  int* bnd = (int*)(ws + 59300000);
  int* pmeta = (int*)(ws + 59500000);
  if (ws_size < (size_t)61500000) return;

  const int NB = (V_N + 255) / 256;  // 196 scan blocks

  WPtrs p;
  p.w[0] = negW; p.w[1] = vcW1; p.w[2] = vcW2; p.w[3] = ccW1; p.w[4] = ccW2;
  p.w[5] = Wz; p.w[6] = Uz; p.w[7] = Wr; p.w[8] = Ur; p.w[9] = Wh; p.w[10] = Uh;

  hipMemsetAsync(ws + 58300000, 0, (size_t)200000, stream);  // cnt
  // fused prep + meta + bnd + hist (hist needs cnt zeroed by the memset)
  hipLaunchKernelGGL(k_front, dim3(3270), dim3(256), 0, stream, p, wt,
                     lit_var, lit_sign, lit_clause, pmeta, bnd, clause_var,
                     cnt, dst);

  hipLaunchKernelGGL(k_scan_pre, dim3(NB), dim3(256), 0, stream, cnt, bsum);
  hipLaunchKernelGGL(k_scan_post, dim3(NB), dim3(256), 0, stream, cnt, bsum,
                     col_start, NB);

  hipLaunchKernelGGL(k_tables, dim3((V_N + 31) / 32), dim3(256), 0, stream,
                     vars, wt + 0, negb, wt + 16384, vcb1, wt + 2 * 16384, vcb2,
                     t_pos, t_neg);

  hipLaunchKernelGGL(k_sc_clause, dim3((C_N + 31) / 32), dim3(256), 0, stream,
                     pmeta, bnd, t_pos, t_neg, dst, col_start, clause_var,
                     wt + 3 * 16384, ccb1, wt + 4 * 16384, ccb2, crows);

  hipLaunchKernelGGL(k_gru, dim3((V_N + 31) / 32), dim3(256), 0, stream,
                     vars, crows, col_start,
                     wt + 5 * 16384, wt + 6 * 16384, wt + 7 * 16384,
                     wt + 8 * 16384, wt + 9 * 16384, wt + 10 * 16384,
                     (float*)d_out);
}